// Round 9
// baseline (91.590 us; speedup 1.0000x reference)
//
#include <hip/hip_runtime.h>

typedef __attribute__((ext_vector_type(8))) short short8;
typedef __attribute__((ext_vector_type(4))) float f32x4;
typedef __attribute__((ext_vector_type(4))) unsigned short us4;

constexpr int NB = 8, NC = 256, IH = 64, IW = 96;
constexpr int PATCH = 21, RAD = 10;
constexpr int TI = 8, TJ = 8;            // pixel tile
constexpr int WIN = 28, NWIN = 784;      // x2 window per tile
constexpr int KC = 32, NKS = NC / KC;    // channel chunking
constexpr int PLANE = IH * IW;
constexpr int PH = IH + 2 * RAD, PW = IW + 2 * RAD;   // 84 x 116 padded x2
constexpr int NBCH = NWIN * 4;           // 3136 B-chunks (16B) per K-step (B only now)
// K-major bf16 workspace layouts: x1k[b][ks][64][96][32], x2k[b][ks][84][116][32]
constexpr int ASTR = IH * IW * KC;       // per-ks stride in x1k (elements)
constexpr int BSTR = PH * PW * KC;       // per-ks stride in x2k
constexpr size_t X1T_ELEMS = (size_t)NB * NKS * ASTR;   // 12.58M
constexpr size_t X2P_ELEMS = (size_t)NB * NKS * BSTR;   // 19.96M
constexpr int GSTR = 65;                 // G-chunk m-stride (floats): diag reads bank +1

__device__ __forceinline__ unsigned short f2bf(float f) {
  unsigned u = __builtin_bit_cast(unsigned, f);
  u += 0x7fffu + ((u >> 16) & 1u);       // RNE
  return (unsigned short)(u >> 16);
}

// ---- pre-pass 1: x1 NCHW fp32 -> K-major [b][ks][i][j][32] bf16 ----
__global__ __launch_bounds__(256) void x1_to_kmajor(
    const float* __restrict__ src, unsigned short* __restrict__ dst) {
  __shared__ float lsf[32 * 97];
  const int blk = blockIdx.x;            // b*512 + i*8 + ct
  const int ct = blk & 7, i = (blk >> 3) & 63, b = blk >> 9;
  const int c0 = ct * 32, t = threadIdx.x;
  const float* sp = src + ((size_t)b * NC + c0) * PLANE + (size_t)i * IW;
#pragma unroll
  for (int k = 0; k < 12; ++k) {
    int idx = k * 256 + t;
    int c = idx / 96, j = idx - c * 96;
    lsf[c * 97 + j] = sp[(size_t)c * PLANE + j];
  }
  __syncthreads();
  unsigned short* dp = dst + (((size_t)(b * NKS + ct) * IH + i) * IW) * KC;
#pragma unroll
  for (int k = 0; k < 3; ++k) {          // 96 j x 8 cq -> contiguous 8B writes
    int o = k * 256 + t;
    int j = o >> 3, cq = o & 7;
    us4 v = {f2bf(lsf[(cq * 4 + 0) * 97 + j]), f2bf(lsf[(cq * 4 + 1) * 97 + j]),
             f2bf(lsf[(cq * 4 + 2) * 97 + j]), f2bf(lsf[(cq * 4 + 3) * 97 + j])};
    *(us4*)&dp[(size_t)j * KC + cq * 4] = v;
  }
}

// ---- pre-pass 2: x2 NCHW fp32 -> K-major halo-padded [b][ks][84][116][32], halo=0 ----
__global__ __launch_bounds__(256) void x2_to_kmajor_pad(
    const float* __restrict__ src, unsigned short* __restrict__ dst) {
  __shared__ float lsf[32 * 97];
  const int blk = blockIdx.x;            // b*(84*8) + i*8 + ct
  const int ct = blk & 7, i = (blk >> 3) % PH, b = blk / (PH * 8);
  const int c0 = ct * 32, t = threadIdx.x;
  const int isrc = i - RAD;
  const bool rowok = (unsigned)isrc < (unsigned)IH;
  if (rowok) {
    const float* sp = src + ((size_t)b * NC + c0) * PLANE + (size_t)isrc * IW;
#pragma unroll
    for (int k = 0; k < 12; ++k) {
      int idx = k * 256 + t;
      int c = idx / 96, j = idx - c * 96;
      lsf[c * 97 + j] = sp[(size_t)c * PLANE + j];
    }
  }
  __syncthreads();
  unsigned short* dp = dst + (((size_t)(b * NKS + ct) * PH + i) * PW) * KC;
#pragma unroll
  for (int k = 0; k < 4; ++k) {          // 116 j x 8 cq = 928 items
    int o = k * 256 + t;
    if (o < PW * 8) {
      int j = o >> 3, cq = o & 7;
      int jsrc = j - RAD;
      us4 v = {0, 0, 0, 0};
      if (rowok && (unsigned)jsrc < (unsigned)IW)
        v = us4{f2bf(lsf[(cq * 4 + 0) * 97 + jsrc]), f2bf(lsf[(cq * 4 + 1) * 97 + jsrc]),
                f2bf(lsf[(cq * 4 + 2) * 97 + jsrc]), f2bf(lsf[(cq * 4 + 3) * 97 + jsrc])};
      *(us4*)&dp[(size_t)j * KC + cq * 4] = v;
    }
  }
}

// ---- main: 8-wave triple-buffered gload_lds pipeline, A in registers ----
// B staged via gload_lds (3 bufs); A fragments loaded direct global->VGPR,
// 1-deep pipelined (load ks+1 during iter ks). ds_reads/wave/K-step: 11 -> 7.
__global__ __launch_bounds__(512, 2) void corr_pipe8(
    const unsigned short* __restrict__ x1k, const unsigned short* __restrict__ x2k,
    float* __restrict__ out) {
  __shared__ __attribute__((aligned(16))) unsigned short ls[3 * NBCH * 8];  // 150528 B

  const int t = threadIdx.x, lane = t & 63, wv = t >> 6;   // wv 0..7
  const int bid = blockIdx.x;
  const int b = bid & 7;                 // batch -> XCD locality
  const int tile = bid >> 3;
  const int ti = tile / 12, tj = tile - ti * 12;
  const int i0 = ti * TI, j0 = tj * TJ;
  const int cbeg = 6 * wv;               // 7 col-tiles/wave; overlap tiles bitwise-identical
  const int qk = lane >> 4, lr = lane & 15;

  const unsigned short* x1b = x1k + (size_t)b * NKS * ASTR;
  const unsigned short* x2b = x2k + (size_t)b * NKS * BSTR;

  // A-fragment base (per-lane): frag a covers pixels m = 16a + lr
  const unsigned short* srcA =
      x1b + ((size_t)(i0 + (lr >> 3)) * IW + (j0 + (lr & 7))) * KC + qk * 8;
  // frag a offset: +2 rows per a -> 2*IW*KC elements
  constexpr size_t AOFF = (size_t)2 * IW * KC;

  // per-thread ks=0 source addresses for the 7 B stage slots (q = it*512 + t)
  const unsigned short* srcp[7];
#pragma unroll
  for (int it = 0; it < 7; ++it) {
    int q = it * 512 + t;
    if (q < NBCH) {                       // B chunk: invert slot swizzle
      int w = ((q >> 3) << 1) | (((q >> 2) ^ (q >> 4)) & 1);
      int c4 = (q & 3) ^ (w & 3);
      int wi = w / WIN, wj = w - wi * WIN;
      srcp[it] = x2b + ((size_t)(i0 + wi) * PW + (j0 + wj)) * KC + c4 * 8;
    } else {
      srcp[it] = x2b;                     // unused lanes of slot 6
    }
  }

  f32x4 acc[4][7];
#pragma unroll
  for (int a = 0; a < 4; ++a)
#pragma unroll
    for (int cc = 0; cc < 7; ++cc) acc[a][cc] = (f32x4){0.f, 0.f, 0.f, 0.f};

  short8 aP0, aP1, aP2, aP3;   // A frags for current ks
  short8 aN0, aN1, aN2, aN3;   // A frags for next ks

#define ALOAD(D0, D1, D2, D3, KS)                                                   \
  {                                                                                 \
    const unsigned short* ap = srcA + (size_t)(KS) * ASTR;                          \
    D0 = *(const short8*)(ap);                                                      \
    D1 = *(const short8*)(ap + AOFF);                                               \
    D2 = *(const short8*)(ap + 2 * AOFF);                                           \
    D3 = *(const short8*)(ap + 3 * AOFF);                                           \
  }

// B-only staging: slots 0-5 all threads (3072 chunks), slot 6 wave 0 (64).
// Per-wave gload_lds count: wv0 = 7, wv1-7 = 6.
#define STAGE(BUF, KS)                                                              \
  {                                                                                 \
    unsigned short* lb = &ls[(BUF) * NBCH * 8];                                     \
    _Pragma("unroll")                                                               \
    for (int it = 0; it < 6; ++it)                                                  \
      __builtin_amdgcn_global_load_lds(                                             \
          (const void*)(srcp[it] + (size_t)(KS) * BSTR),                            \
          (void*)(lb + (it * 512 + wv * 64) * 8), 16, 0, 0);                        \
    if (wv == 0)                                                                    \
      __builtin_amdgcn_global_load_lds(                                             \
          (const void*)(srcp[6] + (size_t)(KS) * BSTR),                             \
          (void*)(lb + 3072 * 8), 16, 0, 0);                                        \
  }

#define COMPUTE(BUF, A0, A1, A2, A3)                                                \
  {                                                                                 \
    const unsigned short* lb = &ls[(BUF) * NBCH * 8];                               \
    _Pragma("unroll")                                                               \
    for (int cc = 0; cc < 7; ++cc) {                                                \
      int wrow = 16 * (cbeg + cc) + lr;                                             \
      int slot = (4 * wrow + qk) ^ (lr & 7);                                        \
      short8 bf = *(const short8*)(lb + slot * 8);                                  \
      acc[0][cc] = __builtin_amdgcn_mfma_f32_16x16x32_bf16(A0, bf, acc[0][cc], 0, 0, 0); \
      acc[1][cc] = __builtin_amdgcn_mfma_f32_16x16x32_bf16(A1, bf, acc[1][cc], 0, 0, 0); \
      acc[2][cc] = __builtin_amdgcn_mfma_f32_16x16x32_bf16(A2, bf, acc[2][cc], 0, 0, 0); \
      acc[3][cc] = __builtin_amdgcn_mfma_f32_16x16x32_bf16(A3, bf, acc[3][cc], 0, 0, 0); \
    }                                                                               \
  }

  // prologue: A(0) to regs; stage ks=0,1
  ALOAD(aP0, aP1, aP2, aP3, 0)
  STAGE(0, 0)
  STAGE(1, 1)

  // Per iter ks: issue A(ks+1) + STAGE(ks+2), then counted vmcnt drains
  // stage(ks) AND A(ks) ("leave newest N" is issue-order-robust: everything
  // newer than stage(ks) is exactly {stage(ks+1), A(ks+1), stage(ks+2)}).
  // Steady leave: wv0 7+4+7=18, else 6+4+6=16. Iter6: 4+7=11 / 4+6=10.
#define ITER(KS, AC0, AC1, AC2, AC3, AN0_, AN1_, AN2_, AN3_, VMW0, VMW)            \
  if ((KS) < 7) ALOAD(AN0_, AN1_, AN2_, AN3_, (KS) + 1)                            \
  if ((KS) < 6) STAGE(((KS) + 2) % 3, (KS) + 2)                                    \
  if (wv == 0) { asm volatile("s_waitcnt vmcnt(" #VMW0 ")" ::: "memory"); }        \
  else         { asm volatile("s_waitcnt vmcnt(" #VMW ")" ::: "memory"); }         \
  asm volatile("s_barrier" ::: "memory");                                          \
  COMPUTE((KS) % 3, AC0, AC1, AC2, AC3)                                            \
  asm volatile("s_barrier" ::: "memory");

  ITER(0, aP0, aP1, aP2, aP3, aN0, aN1, aN2, aN3, 18, 16)
  ITER(1, aN0, aN1, aN2, aN3, aP0, aP1, aP2, aP3, 18, 16)
  ITER(2, aP0, aP1, aP2, aP3, aN0, aN1, aN2, aN3, 18, 16)
  ITER(3, aN0, aN1, aN2, aN3, aP0, aP1, aP2, aP3, 18, 16)
  ITER(4, aP0, aP1, aP2, aP3, aN0, aN1, aN2, aN3, 18, 16)
  ITER(5, aN0, aN1, aN2, aN3, aP0, aP1, aP2, aP3, 18, 16)
  ITER(6, aP0, aP1, aP2, aP3, aN0, aN1, aN2, aN3, 11, 10)
  ITER(7, aN0, aN1, aN2, aN3, aP0, aP1, aP2, aP3, 0, 0)
#undef ITER
#undef COMPUTE
#undef STAGE
#undef ALOAD

  // ---- epilogue: LDS diagonal transpose -> coalesced 32B row-segment stores ----
  // (validated R7/R8 structure; 512 threads, acc[4][7], m = 16a + 4qk + r)
  float* gf = (float*)ls;
#pragma unroll
  for (int ch = 0; ch < 2; ++ch) {
    __syncthreads();                     // full drain: staging reads/writes done
    const int n0 = ch ? 384 : 0;
#pragma unroll
    for (int a = 0; a < 4; ++a)
#pragma unroll
      for (int cc = 0; cc < 7; ++cc) {
        int ccg = cbeg + cc;
        if (ch ? (ccg >= 24) : (ccg <= 24)) {
          int nl = 16 * ccg + lr - n0;
          int mb = 16 * a + 4 * qk;
          float* gp = &gf[nl * GSTR + mb];
          gp[0] = acc[a][cc][0]; gp[1] = acc[a][cc][1];
          gp[2] = acc[a][cc][2]; gp[3] = acc[a][cc][3];
        }
      }
    __syncthreads();
    // 1764 segments per chunk: s = pidx*21 + pj; pidx enumerates (ii,pi) pairs
    // ch0: ii-group k has 14-k pi's (pi=rem); ch1: 7+k pi's (pi=14-k+rem).
    for (int s = t; s < 1764; s += 512) {
      int pidx = s / 21, pj = s - pidx * 21;
      int ii = 0, rem = pidx, stop = 0;
#pragma unroll
      for (int k = 0; k < 7; ++k) {
        int cnt = ch ? (7 + k) : (14 - k);
        int go = (!stop) && (rem >= cnt);
        rem -= go ? cnt : 0;
        ii += go;
        stop |= !go;
      }
      int pi = ch ? (14 - ii + rem) : rem;
      int nl = 28 * (pi + ii) + pj - n0;
      int ms = 8 * ii;
      float g[8];
#pragma unroll
      for (int e = 0; e < 8; ++e) g[e] = gf[(nl + e) * GSTR + ms + e];
      float* op = out + ((((size_t)b * PATCH + pi) * PATCH + pj) * IH + (i0 + ii)) * IW + j0;
      f32x4 v0 = {g[0], g[1], g[2], g[3]};
      f32x4 v1 = {g[4], g[5], g[6], g[7]};
      *(f32x4*)op = v0;
      *(f32x4*)(op + 4) = v1;
    }
  }
}

// ---------------- fallback (R1, validated): NCHW fp32 in-kernel ----------------
constexpr int LDKF = 40;
__global__ __launch_bounds__(512, 2) void corr_mfma_fb(
    const float* __restrict__ x1, const float* __restrict__ x2, float* __restrict__ out) {
  __shared__ __attribute__((aligned(16))) unsigned short lsA[64 * LDKF];
  __shared__ __attribute__((aligned(16))) unsigned short lsB[NWIN * LDKF];
  const int t = threadIdx.x;
  const int b = blockIdx.y;
  const int ti = blockIdx.x / 12, tj = blockIdx.x % 12;
  const int i0 = ti * TI, j0 = tj * TJ;
  const int lane = t & 63, wv = t >> 6;
  const int mtp = wv >> 2, cg = wv & 3, cbeg = cg * 12;
  const int qk = lane >> 4, lr = lane & 15;
  f32x4 acc[2][13];
#pragma unroll
  for (int a = 0; a < 2; ++a)
#pragma unroll
    for (int cc = 0; cc < 13; ++cc) acc[a][cc] = (f32x4){0.f, 0.f, 0.f, 0.f};
  const int am = t & 63, ak4 = t >> 6;
  const int aii = am >> 3, ajj = am & 7;
  const float* x1p = x1 + ((size_t)b * NC + 4 * ak4) * PLANE + (size_t)(i0 + aii) * IW + (j0 + ajj);
  const float* x2b = x2 + (size_t)b * NC * PLANE;
  for (int ks = 0; ks < NKS; ++ks) {
    __syncthreads();
    {
      const float* p = x1p + (size_t)ks * KC * PLANE;
      us4 v = {f2bf(p[0]), f2bf(p[PLANE]), f2bf(p[2 * PLANE]), f2bf(p[3 * PLANE])};
      *(us4*)&lsA[am * LDKF + 4 * ak4] = v;
    }
    for (int w = t; w < NWIN; w += 512) {
      const int wi = w / WIN, wj = w - wi * WIN;
      const int gi = i0 - RAD + wi, gj = j0 - RAD + wj;
      const bool ok = ((unsigned)gi < (unsigned)IH) && ((unsigned)gj < (unsigned)IW);
      const float* p = x2b + ((size_t)(ks * KC) * IH + gi) * IW + gj;
      unsigned short* dst = &lsB[w * LDKF];
#pragma unroll
      for (int k4 = 0; k4 < 8; ++k4) {
        const float* q = p + (size_t)(4 * k4) * PLANE;
        us4 v = {f2bf(ok ? q[0] : 0.f), f2bf(ok ? q[PLANE] : 0.f),
                 f2bf(ok ? q[2 * PLANE] : 0.f), f2bf(ok ? q[3 * PLANE] : 0.f)};
        *(us4*)&dst[4 * k4] = v;
      }
    }
    __syncthreads();
    short8 a0 = *(const short8*)&lsA[(32 * mtp + lr) * LDKF + 8 * qk];
    short8 a1 = *(const short8*)&lsA[(32 * mtp + 16 + lr) * LDKF + 8 * qk];
#pragma unroll
    for (int cc = 0; cc < 13; ++cc) {
      const int wrow = 16 * (cbeg + cc) + lr;
      short8 bf = *(const short8*)&lsB[wrow * LDKF + 8 * qk];
      acc[0][cc] = __builtin_amdgcn_mfma_f32_16x16x32_bf16(a0, bf, acc[0][cc], 0, 0, 0);
      acc[1][cc] = __builtin_amdgcn_mfma_f32_16x16x32_bf16(a1, bf, acc[1][cc], 0, 0, 0);
    }
  }
#pragma unroll
  for (int a = 0; a < 2; ++a) {
    const int mb = 16 * (2 * mtp + a) + qk * 4;
#pragma unroll
    for (int cc = 0; cc < 13; ++cc) {
      if (cg > 0 && cc == 0) continue;
      const int n = 16 * (cbeg + cc) + lr;
      const int wi = n / WIN, wj = n - wi * WIN;
#pragma unroll
      for (int r = 0; r < 4; ++r) {
        const int m = mb + r;
        const int ii = m >> 3, jj = m & 7;
        const int pi = wi - ii, pj = wj - jj;
        if ((unsigned)pi < (unsigned)PATCH && (unsigned)pj < (unsigned)PATCH)
          out[((((size_t)b * PATCH + pi) * PATCH + pj) * IH + (i0 + ii)) * IW + (j0 + jj)] =
              acc[a][cc][r];
      }
    }
  }
}

extern "C" void kernel_launch(void* const* d_in, const int* in_sizes, int n_in,
                              void* d_out, int out_size, void* d_ws, size_t ws_size,
                              hipStream_t stream) {
  const float* x1 = (const float*)d_in[0];
  const float* x2 = (const float*)d_in[1];
  float* out = (float*)d_out;
  const size_t need = (X1T_ELEMS + X2P_ELEMS) * sizeof(unsigned short);  // ~65.1 MB
  if (ws_size >= need) {
    unsigned short* x1k = (unsigned short*)d_ws;
    unsigned short* x2k = x1k + X1T_ELEMS;
    x1_to_kmajor<<<NB * IH * 8, 256, 0, stream>>>(x1, x1k);
    x2_to_kmajor_pad<<<NB * PH * 8, 256, 0, stream>>>(x2, x2k);
    corr_pipe8<<<NB * 96, 512, 0, stream>>>(x1k, x2k, out);
  } else {
    dim3 grid(96, NB);
    corr_mfma_fb<<<grid, 512, 0, stream>>>(x1, x2, out);
  }
}

// Round 10
// 86.388 us; speedup vs baseline: 1.0602x; 1.0602x over previous
//
#include <hip/hip_runtime.h>

typedef __attribute__((ext_vector_type(8))) short short8;
typedef __attribute__((ext_vector_type(4))) float f32x4;
typedef __attribute__((ext_vector_type(4))) unsigned short us4;

constexpr int NB = 8, NC = 256, IH = 64, IW = 96;
constexpr int PATCH = 21, RAD = 10;
constexpr int TI = 8, TJ = 8;            // pixel tile
constexpr int WIN = 28, NWIN = 784;      // x2 window per tile
constexpr int KC = 32, NKS = NC / KC;    // channel chunking
constexpr int PLANE = IH * IW;
constexpr int PH = IH + 2 * RAD, PW = IW + 2 * RAD;   // 84 x 116 padded x2
constexpr int NBCH = NWIN * 4;           // 3136 B-chunks (16B) per K-step
constexpr int NCHUNK = NBCH + 256;       // + 256 A-chunks = 3392
constexpr int BSTR = PH * PW * KC;       // per-ks stride in x2k (elements)
constexpr size_t X2P_ELEMS = (size_t)NB * NKS * BSTR;   // 19.96M
constexpr int GSTR = 65;                 // G-chunk row stride (floats)

__device__ __forceinline__ unsigned short f2bf(float f) {
  unsigned u = __builtin_bit_cast(unsigned, f);
  u += 0x7fffu + ((u >> 16) & 1u);       // RNE
  return (unsigned short)(u >> 16);
}

// ---- pre-pass: x2 NCHW fp32 -> K-major halo-padded [b][ks][84][116][32], halo=0 ----
__global__ __launch_bounds__(256) void x2_to_kmajor_pad(
    const float* __restrict__ src, unsigned short* __restrict__ dst) {
  __shared__ float lsf[32 * 97];
  const int blk = blockIdx.x;            // b*(84*8) + i*8 + ct
  const int ct = blk & 7, i = (blk >> 3) % PH, b = blk / (PH * 8);
  const int c0 = ct * 32, t = threadIdx.x;
  const int isrc = i - RAD;
  const bool rowok = (unsigned)isrc < (unsigned)IH;
  if (rowok) {
    const float* sp = src + ((size_t)b * NC + c0) * PLANE + (size_t)isrc * IW;
#pragma unroll
    for (int k = 0; k < 12; ++k) {
      int idx = k * 256 + t;
      int c = idx / 96, j = idx - c * 96;
      lsf[c * 97 + j] = sp[(size_t)c * PLANE + j];
    }
  }
  __syncthreads();
  unsigned short* dp = dst + (((size_t)(b * NKS + ct) * PH + i) * PW) * KC;
#pragma unroll
  for (int k = 0; k < 4; ++k) {          // 116 j x 8 cq = 928 items
    int o = k * 256 + t;
    if (o < PW * 8) {
      int j = o >> 3, cq = o & 7;
      int jsrc = j - RAD;
      us4 v = {0, 0, 0, 0};
      if (rowok && (unsigned)jsrc < (unsigned)IW)
        v = us4{f2bf(lsf[(cq * 4 + 0) * 97 + jsrc]), f2bf(lsf[(cq * 4 + 1) * 97 + jsrc]),
                f2bf(lsf[(cq * 4 + 2) * 97 + jsrc]), f2bf(lsf[(cq * 4 + 3) * 97 + jsrc])};
      *(us4*)&dp[(size_t)j * KC + cq * 4] = v;
    }
  }
}

// ---- main: 8-wave triple-buffered pipeline; B via gload_lds, A staged in-kernel
//      from NCHW fp32 (4 scalar loads + f2bf + ds_write_b64 per thread per K-step).
__global__ __launch_bounds__(512, 2) void corr_pipe8(
    const float* __restrict__ x1, const unsigned short* __restrict__ x2k,
    float* __restrict__ out) {
  __shared__ __attribute__((aligned(16))) unsigned short ls[3 * NCHUNK * 8];  // 162816 B

  const int t = threadIdx.x, lane = t & 63, wv = t >> 6;   // wv 0..7
  const int bid = blockIdx.x;
  const int b = bid & 7;                 // batch -> XCD locality
  const int tile = bid >> 3;
  const int ti = tile / 12, tj = tile - ti * 12;
  const int i0 = ti * TI, j0 = tj * TJ;
  const int cbeg = 6 * wv;               // 7 col-tiles/wave; overlap tiles bitwise-identical
  const int qk = lane >> 4, lr = lane & 15;

  const unsigned short* x2b = x2k + (size_t)b * NKS * BSTR;

  // B stage sources (slots 0-5 all threads, slot 6 wave 0): invert slot swizzle
  const unsigned short* srcp[7];
#pragma unroll
  for (int it = 0; it < 7; ++it) {
    int q = it * 512 + t;
    if (q < NBCH) {
      int w = ((q >> 3) << 1) | (((q >> 2) ^ (q >> 4)) & 1);
      int c4 = (q & 3) ^ (w & 3);
      int wi = w / WIN, wj = w - wi * WIN;
      srcp[it] = x2b + ((size_t)(i0 + wi) * PW + (j0 + wj)) * KC + c4 * 8;
    } else {
      srcp[it] = x2b;                     // unused lanes of slot 6
    }
  }

  // A staging: thread owns one us4 = pixel am, channel-quad acq
  const int am = t & 63, acq = t >> 6;    // acq 0..7
  const int aqk = acq >> 1, ah = acq & 1;
  const float* srcA = x1 + ((size_t)(b * NC) + acq * 4) * PLANE
                         + (size_t)(i0 + (am >> 3)) * IW + (j0 + (am & 7));
  const int aoff = (NBCH + ((4 * am + aqk) ^ (am & 7))) * 8 + ah * 4;  // ushort off

  f32x4 acc[4][7];
#pragma unroll
  for (int a = 0; a < 4; ++a)
#pragma unroll
    for (int cc = 0; cc < 7; ++cc) acc[a][cc] = (f32x4){0.f, 0.f, 0.f, 0.f};

  float fA0, fA1, fA2, fA3, fB0, fB1, fB2, fB3;   // two A reg sets

#define ALOAD(S, KS)                                                                \
  {                                                                                 \
    const float* p = srcA + (size_t)(KS) * KC * PLANE;                              \
    f##S##0 = p[0]; f##S##1 = p[PLANE]; f##S##2 = p[2 * PLANE]; f##S##3 = p[3 * PLANE]; \
  }
#define APACK(S, BUF)                                                               \
  {                                                                                 \
    us4 v = {f2bf(f##S##0), f2bf(f##S##1), f2bf(f##S##2), f2bf(f##S##3)};           \
    *(us4*)&ls[(BUF) * NCHUNK * 8 + aoff] = v;                                      \
  }

#define STAGE(BUF, KS)                                                              \
  {                                                                                 \
    unsigned short* lb = &ls[(BUF) * NCHUNK * 8];                                   \
    _Pragma("unroll")                                                               \
    for (int it = 0; it < 6; ++it)                                                  \
      __builtin_amdgcn_global_load_lds(                                             \
          (const void*)(srcp[it] + (size_t)(KS) * BSTR),                            \
          (void*)(lb + (it * 512 + wv * 64) * 8), 16, 0, 0);                        \
    if (wv == 0)                                                                    \
      __builtin_amdgcn_global_load_lds(                                             \
          (const void*)(srcp[6] + (size_t)(KS) * BSTR),                             \
          (void*)(lb + 3072 * 8), 16, 0, 0);                                        \
  }

#define COMPUTE(BUF)                                                                \
  {                                                                                 \
    const unsigned short* lb = &ls[(BUF) * NCHUNK * 8];                             \
    short8 af0 = *(const short8*)(lb + (NBCH + ((4 * lr + qk) ^ (lr & 7))) * 8);          \
    short8 af1 = *(const short8*)(lb + (NBCH + ((4 * (16 + lr) + qk) ^ (lr & 7))) * 8);   \
    short8 af2 = *(const short8*)(lb + (NBCH + ((4 * (32 + lr) + qk) ^ (lr & 7))) * 8);   \
    short8 af3 = *(const short8*)(lb + (NBCH + ((4 * (48 + lr) + qk) ^ (lr & 7))) * 8);   \
    _Pragma("unroll")                                                               \
    for (int cc = 0; cc < 7; ++cc) {                                                \
      int wrow = 16 * (cbeg + cc) + lr;                                             \
      int slot = (4 * wrow + qk) ^ (lr & 7);                                        \
      short8 bf = *(const short8*)(lb + slot * 8);                                  \
      acc[0][cc] = __builtin_amdgcn_mfma_f32_16x16x32_bf16(af0, bf, acc[0][cc], 0, 0, 0); \
      acc[1][cc] = __builtin_amdgcn_mfma_f32_16x16x32_bf16(af1, bf, acc[1][cc], 0, 0, 0); \
      acc[2][cc] = __builtin_amdgcn_mfma_f32_16x16x32_bf16(af2, bf, acc[2][cc], 0, 0, 0); \
      acc[3][cc] = __builtin_amdgcn_mfma_f32_16x16x32_bf16(af3, bf, acc[3][cc], 0, 0, 0); \
    }                                                                               \
  }

#define VMW(W0, W)                                                                  \
  if (wv == 0) { asm volatile("s_waitcnt vmcnt(" #W0 ")" ::: "memory"); }           \
  else         { asm volatile("s_waitcnt vmcnt(" #W ")" ::: "memory"); }

  // prologue: A0->regs, S0, A1->regs, S1; drain A0 (leave S0+A1+S1=18|16); pack A0->buf0
  ALOAD(A, 0)
  STAGE(0, 0)
  ALOAD(B, 1)
  STAGE(1, 1)
  VMW(18, 16)
  APACK(A, 0)

  // iter ks: issue A(ks+2)+S(ks+2); vmcnt drains S(ks) AND A(ks+1) (leave =
  // S(ks+1)+A(ks+2)+S(ks+2) = 18|16); pack A(ks+1)->buf[(ks+1)%3] (WAR: that A
  // region last read at iter ks-2, 2 barriers ago); lgkmcnt(0) retires the
  // ds_write before the barrier; COMPUTE(ks); barrier protects restaged buffer.
#define ITER(KS, SL, SP, W0, W)                                                     \
  if ((KS) < 6) { ALOAD(SL, (KS) + 2) STAGE(((KS) + 2) % 3, (KS) + 2) }             \
  VMW(W0, W)                                                                        \
  if ((KS) < 7) { APACK(SP, ((KS) + 1) % 3) }                                       \
  asm volatile("s_waitcnt lgkmcnt(0)" ::: "memory");                                \
  asm volatile("s_barrier" ::: "memory");                                           \
  COMPUTE((KS) % 3)                                                                 \
  asm volatile("s_barrier" ::: "memory");

  ITER(0, A, B, 18, 16)   // load A2->sA, pack A1(sB)->buf1
  ITER(1, B, A, 18, 16)   // load A3->sB, pack A2(sA)->buf2
  ITER(2, A, B, 18, 16)
  ITER(3, B, A, 18, 16)
  ITER(4, A, B, 18, 16)
  ITER(5, B, A, 18, 16)   // load A7->sB, pack A6(sA)->buf0
  ITER(6, A, B, 7, 6)     // no loads; drain S6+A7 (leave S7); pack A7(sB)->buf1
  ITER(7, B, A, 0, 0)     // drain S7; no pack
#undef ITER
#undef VMW
#undef COMPUTE
#undef STAGE
#undef APACK
#undef ALOAD

  // ---- epilogue: G transpose in LDS with XOR-swizzled granules ----
  // write: logical m-granule sm=4a+qk at row nl stored at 4*(sm^(nl&7))
  // read:  float m at row: 4*((m>>2)^(row&7)) + (m&3)  (full 32-bank permutation)
  float* gf = (float*)ls;
#pragma unroll
  for (int ch = 0; ch < 2; ++ch) {
    __syncthreads();                     // full drain: staging reads/writes done
    const int n0 = ch ? 384 : 0;
#pragma unroll
    for (int a = 0; a < 4; ++a)
#pragma unroll
      for (int cc = 0; cc < 7; ++cc) {
        int ccg = cbeg + cc;
        if (ch ? (ccg >= 24) : (ccg <= 24)) {
          int nl = 16 * ccg + lr - n0;   // nl&7 == lr&7
          int sm = 4 * a + qk;
          float* gp = &gf[nl * GSTR + 4 * (sm ^ (lr & 7))];
          gp[0] = acc[a][cc][0]; gp[1] = acc[a][cc][1];
          gp[2] = acc[a][cc][2]; gp[3] = acc[a][cc][3];
        }
      }
    __syncthreads();
    // 1764 segments per chunk: s = pidx*21 + pj; pidx enumerates (ii,pi) pairs
    for (int s = t; s < 1764; s += 512) {
      int pidx = s / 21, pj = s - pidx * 21;
      int ii = 0, rem = pidx, stop = 0;
#pragma unroll
      for (int k = 0; k < 7; ++k) {
        int cnt = ch ? (7 + k) : (14 - k);
        int go = (!stop) && (rem >= cnt);
        rem -= go ? cnt : 0;
        ii += go;
        stop |= !go;
      }
      int pi = ch ? (14 - ii + rem) : rem;
      int nl = 28 * (pi + ii) + pj - n0;
      int ms = 8 * ii;
      float g[8];
#pragma unroll
      for (int e = 0; e < 8; ++e) {
        int m = ms + e, row = nl + e;
        g[e] = gf[row * GSTR + 4 * ((m >> 2) ^ (row & 7)) + (m & 3)];
      }
      float* op = out + ((((size_t)b * PATCH + pi) * PATCH + pj) * IH + (i0 + ii)) * IW + j0;
      f32x4 v0 = {g[0], g[1], g[2], g[3]};
      f32x4 v1 = {g[4], g[5], g[6], g[7]};
      *(f32x4*)op = v0;
      *(f32x4*)(op + 4) = v1;
    }
  }
}

// ---------------- fallback (R1, validated): NCHW fp32 in-kernel ----------------
constexpr int LDKF = 40;
__global__ __launch_bounds__(512, 2) void corr_mfma_fb(
    const float* __restrict__ x1, const float* __restrict__ x2, float* __restrict__ out) {
  __shared__ __attribute__((aligned(16))) unsigned short lsA[64 * LDKF];
  __shared__ __attribute__((aligned(16))) unsigned short lsB[NWIN * LDKF];
  const int t = threadIdx.x;
  const int b = blockIdx.y;
  const int ti = blockIdx.x / 12, tj = blockIdx.x % 12;
  const int i0 = ti * TI, j0 = tj * TJ;
  const int lane = t & 63, wv = t >> 6;
  const int mtp = wv >> 2, cg = wv & 3, cbeg = cg * 12;
  const int qk = lane >> 4, lr = lane & 15;
  f32x4 acc[2][13];
#pragma unroll
  for (int a = 0; a < 2; ++a)
#pragma unroll
    for (int cc = 0; cc < 13; ++cc) acc[a][cc] = (f32x4){0.f, 0.f, 0.f, 0.f};
  const int am = t & 63, ak4 = t >> 6;
  const int aii = am >> 3, ajj = am & 7;
  const float* x1p = x1 + ((size_t)b * NC + 4 * ak4) * PLANE + (size_t)(i0 + aii) * IW + (j0 + ajj);
  const float* x2b = x2 + (size_t)b * NC * PLANE;
  for (int ks = 0; ks < NKS; ++ks) {
    __syncthreads();
    {
      const float* p = x1p + (size_t)ks * KC * PLANE;
      us4 v = {f2bf(p[0]), f2bf(p[PLANE]), f2bf(p[2 * PLANE]), f2bf(p[3 * PLANE])};
      *(us4*)&lsA[am * LDKF + 4 * ak4] = v;
    }
    for (int w = t; w < NWIN; w += 512) {
      const int wi = w / WIN, wj = w - wi * WIN;
      const int gi = i0 - RAD + wi, gj = j0 - RAD + wj;
      const bool ok = ((unsigned)gi < (unsigned)IH) && ((unsigned)gj < (unsigned)IW);
      const float* p = x2b + ((size_t)(ks * KC) * IH + gi) * IW + gj;
      unsigned short* dst = &lsB[w * LDKF];
#pragma unroll
      for (int k4 = 0; k4 < 8; ++k4) {
        const float* q = p + (size_t)(4 * k4) * PLANE;
        us4 v = {f2bf(ok ? q[0] : 0.f), f2bf(ok ? q[PLANE] : 0.f),
                 f2bf(ok ? q[2 * PLANE] : 0.f), f2bf(ok ? q[3 * PLANE] : 0.f)};
        *(us4*)&dst[4 * k4] = v;
      }
    }
    __syncthreads();
    short8 a0 = *(const short8*)&lsA[(32 * mtp + lr) * LDKF + 8 * qk];
    short8 a1 = *(const short8*)&lsA[(32 * mtp + 16 + lr) * LDKF + 8 * qk];
#pragma unroll
    for (int cc = 0; cc < 13; ++cc) {
      const int wrow = 16 * (cbeg + cc) + lr;
      short8 bf = *(const short8*)&lsB[wrow * LDKF + 8 * qk];
      acc[0][cc] = __builtin_amdgcn_mfma_f32_16x16x32_bf16(a0, bf, acc[0][cc], 0, 0, 0);
      acc[1][cc] = __builtin_amdgcn_mfma_f32_16x16x32_bf16(a1, bf, acc[1][cc], 0, 0, 0);
    }
  }
#pragma unroll
  for (int a = 0; a < 2; ++a) {
    const int mb = 16 * (2 * mtp + a) + qk * 4;
#pragma unroll
    for (int cc = 0; cc < 13; ++cc) {
      if (cg > 0 && cc == 0) continue;
      const int n = 16 * (cbeg + cc) + lr;
      const int wi = n / WIN, wj = n - wi * WIN;
#pragma unroll
      for (int r = 0; r < 4; ++r) {
        const int m = mb + r;
        const int ii = m >> 3, jj = m & 7;
        const int pi = wi - ii, pj = wj - jj;
        if ((unsigned)pi < (unsigned)PATCH && (unsigned)pj < (unsigned)PATCH)
          out[((((size_t)b * PATCH + pi) * PATCH + pj) * IH + (i0 + ii)) * IW + (j0 + jj)] =
              acc[a][cc][r];
      }
    }
  }
}

extern "C" void kernel_launch(void* const* d_in, const int* in_sizes, int n_in,
                              void* d_out, int out_size, void* d_ws, size_t ws_size,
                              hipStream_t stream) {
  const float* x1 = (const float*)d_in[0];
  const float* x2 = (const float*)d_in[1];
  float* out = (float*)d_out;
  const size_t need = X2P_ELEMS * sizeof(unsigned short);   // ~39.9 MB
  if (ws_size >= need) {
    unsigned short* x2k = (unsigned short*)d_ws;
    x2_to_kmajor_pad<<<NB * PH * 8, 256, 0, stream>>>(x2, x2k);
    corr_pipe8<<<NB * 96, 512, 0, stream>>>(x1, x2k, out);
  } else {
    dim3 grid(96, NB);
    corr_mfma_fb<<<grid, 512, 0, stream>>>(x1, x2, out);
  }
}